// Round 1
// baseline (819.296 us; speedup 1.0000x reference)
//
#include <hip/hip_runtime.h>
#include <hip/hip_bf16.h>
#include <stdint.h>

#define M_TOTAL 16384   // BATCH * SEQ
#define N_TOTAL 4096    // OUT_FEATURES
#define K_TOTAL 4096    // IN_FEATURES

#define BM 128
#define BN 128
#define BK 32

typedef __attribute__((ext_vector_type(4))) float f32x4;
typedef __attribute__((ext_vector_type(4))) int   i32x4;
typedef __attribute__((ext_vector_type(8))) short s16x8;
typedef __attribute__((ext_vector_type(4))) short s16x4;

__device__ __forceinline__ unsigned short f32_to_bf16_rne(float f) {
  union { float f; unsigned u; } c; c.f = f;
  unsigned r = (c.u + 0x7fffu + ((c.u >> 16) & 1u)) >> 16;
  return (unsigned short)r;
}

// x fp32 (M,K) -> bf16 (M,K), vectorized float4 -> ushort4
__global__ void cvt_x_kernel(const float* __restrict__ x,
                             unsigned short* __restrict__ xb) {
  const int n4 = M_TOTAL * (K_TOTAL / 4);
  int idx = blockIdx.x * blockDim.x + threadIdx.x;
  int stride = gridDim.x * blockDim.x;
  const f32x4* xv = (const f32x4*)x;
  s16x4* ov = (s16x4*)xb;
  for (int i = idx; i < n4; i += stride) {
    f32x4 v = xv[i];
    s16x4 o;
#pragma unroll
    for (int j = 0; j < 4; ++j) o[j] = (short)f32_to_bf16_rne(v[j]);
    ov[i] = o;
  }
}

// packed int4 (one byte per int32 elem, per harness int convention)
// -> bf16 integer values (N, K) row-major ("B^T" layout).
// low nibble -> even k, high nibble -> odd k (arithmetic sign extension).
__global__ void dequant_w_kernel(const int* __restrict__ wq,
                                 unsigned short* __restrict__ wb) {
  const int n = (N_TOTAL * (K_TOTAL / 2)) / 4;  // groups of 4 packed bytes
  int idx = blockIdx.x * blockDim.x + threadIdx.x;
  int stride = gridDim.x * blockDim.x;
  const i32x4* wv = (const i32x4*)wq;
  s16x8* ov = (s16x8*)wb;
  for (int i = idx; i < n; i += stride) {
    i32x4 w = wv[i];
    s16x8 o;
#pragma unroll
    for (int j = 0; j < 4; ++j) {
      int b = w[j];
      int lo = ((b & 0xF) ^ 8) - 8;
      int hi = (((b >> 4) & 0xF) ^ 8) - 8;
      union { float f; unsigned u; } cl, ch;
      cl.f = (float)lo; ch.f = (float)hi;
      o[2 * j]     = (short)(cl.u >> 16);   // exact for small ints
      o[2 * j + 1] = (short)(ch.u >> 16);
    }
    ov[i] = o;
  }
}

// m97-structure bf16 GEMM: C(M,N) = A(M,K) * B(N,K)^T, epilogue scale+bias.
__global__ __launch_bounds__(256) void gemm_bf16_kernel(
    const unsigned short* __restrict__ A,   // M x K bf16
    const unsigned short* __restrict__ B,   // N x K bf16 (int values)
    const float* __restrict__ scales,
    const float* __restrict__ bias,
    float* __restrict__ C) {
  __shared__ unsigned short As[BM * BK];  // 8 KB
  __shared__ unsigned short Bs[BN * BK];  // 8 KB

  const int t = threadIdx.x;
  const int bm = blockIdx.x;
  const int bn = blockIdx.y;
  const int wave = t >> 6;
  const int lane = t & 63;
  const int wr = (wave >> 1) * 64;  // wave row offset in tile
  const int wc = (wave & 1) * 64;   // wave col offset in tile
  const int fr = lane & 15;         // fragment row (A) / col (B,C)
  const int kg = lane >> 4;         // k-group: k offset = kg*8

  f32x4 acc[4][4] = {};

  const unsigned short* Ab = A + (size_t)bm * BM * K_TOTAL;
  const unsigned short* Bb = B + (size_t)bn * BN * K_TOTAL;
  const int srow = t >> 2;          // staging row 0..63 (+64 for 2nd issue)
  const int scol = (t & 3) * 8;     // staging col in elements

  for (int kt = 0; kt < K_TOTAL; kt += BK) {
    const unsigned short* ga = Ab + (size_t)srow * K_TOTAL + kt + scol;
    const unsigned short* gb = Bb + (size_t)srow * K_TOTAL + kt + scol;
    __builtin_amdgcn_global_load_lds(
        (const __attribute__((address_space(1))) unsigned int*)ga,
        (__attribute__((address_space(3))) unsigned int*)(As + t * 8), 16, 0, 0);
    __builtin_amdgcn_global_load_lds(
        (const __attribute__((address_space(1))) unsigned int*)(ga + (size_t)64 * K_TOTAL),
        (__attribute__((address_space(3))) unsigned int*)(As + 2048 + t * 8), 16, 0, 0);
    __builtin_amdgcn_global_load_lds(
        (const __attribute__((address_space(1))) unsigned int*)gb,
        (__attribute__((address_space(3))) unsigned int*)(Bs + t * 8), 16, 0, 0);
    __builtin_amdgcn_global_load_lds(
        (const __attribute__((address_space(1))) unsigned int*)(gb + (size_t)64 * K_TOTAL),
        (__attribute__((address_space(3))) unsigned int*)(Bs + 2048 + t * 8), 16, 0, 0);
    __syncthreads();  // compiler drains vmcnt before barrier

    s16x8 af[4], bfr[4];
#pragma unroll
    for (int m = 0; m < 4; ++m)
      af[m] = *(const s16x8*)&As[(wr + m * 16 + fr) * BK + kg * 8];
#pragma unroll
    for (int n = 0; n < 4; ++n)
      bfr[n] = *(const s16x8*)&Bs[(wc + n * 16 + fr) * BK + kg * 8];
#pragma unroll
    for (int m = 0; m < 4; ++m)
#pragma unroll
      for (int n = 0; n < 4; ++n)
        acc[m][n] = __builtin_amdgcn_mfma_f32_16x16x32_bf16(af[m], bfr[n],
                                                            acc[m][n], 0, 0, 0);
    __syncthreads();  // protect LDS before next stage
  }

  // Epilogue: C/D layout col = lane&15, row = (lane>>4)*4 + reg (m89/m91).
  const int row0 = bm * BM + wr + kg * 4;
  const int col0 = bn * BN + wc + fr;
#pragma unroll
  for (int n = 0; n < 4; ++n) {
    const int go = col0 + n * 16;
    const float s = scales[go];
    const float bv = bias[go];
#pragma unroll
    for (int m = 0; m < 4; ++m) {
      const int gm = row0 + m * 16;
#pragma unroll
      for (int r = 0; r < 4; ++r)
        C[(size_t)(gm + r) * N_TOTAL + go] = acc[m][n][r] * s + bv;
    }
  }
}

// Fallback if workspace is too small: correct but slow.
__global__ void naive_int4_kernel(const float* __restrict__ x,
                                  const int* __restrict__ wq,
                                  const float* __restrict__ scales,
                                  const float* __restrict__ bias,
                                  float* __restrict__ out) {
  size_t idx = (size_t)blockIdx.x * blockDim.x + threadIdx.x;
  int o = (int)(idx & (N_TOTAL - 1));
  int m = (int)(idx >> 12);
  const float* xr = x + (size_t)m * K_TOTAL;
  const int* wrow = wq + (size_t)o * (K_TOTAL / 2);
  float acc = 0.f;
  for (int j = 0; j < K_TOTAL / 2; ++j) {
    int b = wrow[j];
    int lo = ((b & 0xF) ^ 8) - 8;
    int hi = (((b >> 4) & 0xF) ^ 8) - 8;
    acc += xr[2 * j] * (float)lo + xr[2 * j + 1] * (float)hi;
  }
  out[idx] = acc * scales[o] + bias[o];
}

extern "C" void kernel_launch(void* const* d_in, const int* in_sizes, int n_in,
                              void* d_out, int out_size, void* d_ws, size_t ws_size,
                              hipStream_t stream) {
  const float* x      = (const float*)d_in[0];
  const int*   wq     = (const int*)d_in[1];
  const float* scales = (const float*)d_in[2];
  const float* bias   = (const float*)d_in[3];
  float* out = (float*)d_out;

  const size_t needA = (size_t)M_TOTAL * K_TOTAL * sizeof(unsigned short);  // 128 MB
  const size_t needW = (size_t)N_TOTAL * K_TOTAL * sizeof(unsigned short);  //  32 MB

  if (d_ws != nullptr && ws_size >= needA + needW) {
    unsigned short* Ab = (unsigned short*)d_ws;
    unsigned short* Wb = (unsigned short*)((char*)d_ws + needA);
    cvt_x_kernel<<<2048, 256, 0, stream>>>(x, Ab);
    dequant_w_kernel<<<1024, 256, 0, stream>>>(wq, Wb);
    dim3 grid(M_TOTAL / BM, N_TOTAL / BN);
    gemm_bf16_kernel<<<grid, 256, 0, stream>>>(Ab, Wb, scales, bias, out);
  } else {
    const size_t total = (size_t)M_TOTAL * N_TOTAL;
    naive_int4_kernel<<<(unsigned)(total / 256), 256, 0, stream>>>(x, wq, scales, bias, out);
  }
}

// Round 2
// 594.470 us; speedup vs baseline: 1.3782x; 1.3782x over previous
//
#include <hip/hip_runtime.h>
#include <hip/hip_bf16.h>
#include <stdint.h>

#define M_TOTAL 16384   // BATCH * SEQ
#define N_TOTAL 4096    // OUT_FEATURES
#define K_TOTAL 4096    // IN_FEATURES

#define BM 256
#define BN 256
#define BK 64
#define NT (K_TOTAL / BK)   // 64 K-steps

typedef __attribute__((ext_vector_type(4))) float f32x4;
typedef __attribute__((ext_vector_type(4))) int   i32x4;
typedef __attribute__((ext_vector_type(8))) short s16x8;
typedef __attribute__((ext_vector_type(4))) short s16x4;

__device__ __forceinline__ unsigned short f32_to_bf16_rne(float f) {
  union { float f; unsigned u; } c; c.f = f;
  unsigned r = (c.u + 0x7fffu + ((c.u >> 16) & 1u)) >> 16;
  return (unsigned short)r;
}

// x fp32 (M,K) -> bf16 (M,K)
__global__ void cvt_x_kernel(const float* __restrict__ x,
                             unsigned short* __restrict__ xb) {
  const int n4 = M_TOTAL * (K_TOTAL / 4);
  int idx = blockIdx.x * blockDim.x + threadIdx.x;
  int stride = gridDim.x * blockDim.x;
  const f32x4* xv = (const f32x4*)x;
  s16x4* ov = (s16x4*)xb;
  for (int i = idx; i < n4; i += stride) {
    f32x4 v = xv[i];
    s16x4 o;
#pragma unroll
    for (int j = 0; j < 4; ++j) o[j] = (short)f32_to_bf16_rne(v[j]);
    ov[i] = o;
  }
}

// packed int4 (one byte per int32 elem) -> bf16 integer values (N, K) row-major.
__global__ void dequant_w_kernel(const int* __restrict__ wq,
                                 unsigned short* __restrict__ wb) {
  const int n = (N_TOTAL * (K_TOTAL / 2)) / 4;
  int idx = blockIdx.x * blockDim.x + threadIdx.x;
  int stride = gridDim.x * blockDim.x;
  const i32x4* wv = (const i32x4*)wq;
  s16x8* ov = (s16x8*)wb;
  for (int i = idx; i < n; i += stride) {
    i32x4 w = wv[i];
    s16x8 o;
#pragma unroll
    for (int j = 0; j < 4; ++j) {
      int b = w[j];
      int lo = ((b & 0xF) ^ 8) - 8;
      int hi = (((b >> 4) & 0xF) ^ 8) - 8;
      union { float f; unsigned u; } cl, ch;
      cl.f = (float)lo; ch.f = (float)hi;
      o[2 * j]     = (short)(cl.u >> 16);
      o[2 * j + 1] = (short)(ch.u >> 16);
    }
    ov[i] = o;
  }
}

// 256x256 tile, BK=64, 8 waves (2x4), counted-vmcnt pipelined, T2 LDS swizzle.
__global__ __launch_bounds__(512, 2) void gemm256_kernel(
    const unsigned short* __restrict__ A,   // M x K bf16
    const unsigned short* __restrict__ B,   // N x K bf16 (int values)
    const float* __restrict__ scales,
    const float* __restrict__ bias,
    float* __restrict__ C) {
  // [buf][A=0/B=1][256 rows][64 cols] bf16 = 128 KB total
  __shared__ unsigned short lds[2][2][BM * BK];

  const int t  = threadIdx.x;
  const int l  = t & 63;
  const int w  = t >> 6;        // wave 0..7
  const int wm = w >> 2;        // 0..1 (M half)
  const int wn = w & 3;         // 0..3 (N quarter)
  const int fr = l & 15;
  const int kg = l >> 4;        // 0..3
  const int sx = fr & 7;        // swizzle XOR (row&7 == fr&7 for all frags)

  // T1: bijective XCD swizzle; nwg = 64*16 = 1024, divisible by 8.
  const int wg  = blockIdx.x;
  const int swz = (wg & 7) * (1024 / 8) + (wg >> 3);
  const int bm  = swz & 63;   // M-tile fastest within an XCD chunk
  const int bn  = swz >> 6;

  // Staging: linear LDS dest (global_load_lds), pre-swizzled global source.
  // Lane l writes stored (row = g*64 + w*8 + (l>>3), slot = l&7); that slot
  // must hold logical slot (l&7) ^ (row&7) = (l&7) ^ (l>>3).
  const int rr   = l >> 3;
  const int ssrc = (l & 7) ^ rr;
  const unsigned short* pa = A + (size_t)(bm * BM + w * 8 + rr) * K_TOTAL + ssrc * 8;
  const unsigned short* pb = B + (size_t)(bn * BN + w * 8 + rr) * K_TOTAL + ssrc * 8;
  const int lds_off = w * 512 + l * 8;   // ushort units: w*1024B + l*16B

#define GLL(gp, lp) __builtin_amdgcn_global_load_lds( \
      (const __attribute__((address_space(1))) unsigned int*)(gp), \
      (__attribute__((address_space(3))) unsigned int*)(lp), 16, 0, 0)

  auto stage = [&](int buf, int kt) {
#pragma unroll
    for (int g = 0; g < 4; ++g) {
      GLL(pa + (size_t)g * 64 * K_TOTAL + kt, &lds[buf][0][lds_off + g * 4096]);
      GLL(pb + (size_t)g * 64 * K_TOTAL + kt, &lds[buf][1][lds_off + g * 4096]);
    }
  };

  f32x4 acc[8][4] = {};

  stage(0, 0);
  stage(1, BK);

  for (int t0 = 0; t0 < NT; ++t0) {
    // T4: counted vmcnt — tile t0's 8 loads landed; next tile's 8 stay in flight.
    if (t0 + 1 < NT) { asm volatile("s_waitcnt vmcnt(8)" ::: "memory"); }
    else             { asm volatile("s_waitcnt vmcnt(0)" ::: "memory"); }
    __builtin_amdgcn_sched_barrier(0);
    __builtin_amdgcn_s_barrier();           // barrier-A: buf[cur] fully staged
    __builtin_amdgcn_sched_barrier(0);

    const int cur = t0 & 1;
    const unsigned short* Ab = &lds[cur][0][(wm * 128 + fr) * BK];
    const unsigned short* Bb = &lds[cur][1][(wn * 64 + fr) * BK];
    s16x8 af[8][2], bf[4][2];
#pragma unroll
    for (int kh = 0; kh < 2; ++kh) {
      const int so = ((kh * 4 + kg) ^ sx) * 8;   // T2 swizzled slot
#pragma unroll
      for (int n = 0; n < 4; ++n)
        bf[n][kh] = *(const s16x8*)&Bb[n * 16 * BK + so];
#pragma unroll
      for (int m = 0; m < 8; ++m)
        af[m][kh] = *(const s16x8*)&Ab[m * 16 * BK + so];
    }
    asm volatile("s_waitcnt lgkmcnt(0)" ::: "memory");   // all reads complete
    __builtin_amdgcn_sched_barrier(0);
    __builtin_amdgcn_s_barrier();           // barrier-B: every wave done reading
    __builtin_amdgcn_sched_barrier(0);

    if (t0 + 2 < NT) stage(cur, (t0 + 2) * BK);   // overwrite consumed buffer

    __builtin_amdgcn_s_setprio(1);          // T5
#pragma unroll
    for (int kh = 0; kh < 2; ++kh)
#pragma unroll
      for (int m = 0; m < 8; ++m)
#pragma unroll
        for (int n = 0; n < 4; ++n)
          acc[m][n] = __builtin_amdgcn_mfma_f32_16x16x32_bf16(af[m][kh], bf[n][kh],
                                                              acc[m][n], 0, 0, 0);
    __builtin_amdgcn_s_setprio(0);
  }

  // Epilogue: C/D layout col = lane&15, row = (lane>>4)*4 + reg.
  const int row0 = bm * BM + wm * 128 + kg * 4;
  const int col0 = bn * BN + wn * 64 + fr;
#pragma unroll
  for (int n = 0; n < 4; ++n) {
    const int gc = col0 + n * 16;
    const float s  = scales[gc];
    const float bv = bias[gc];
#pragma unroll
    for (int m = 0; m < 8; ++m) {
      const int gr = row0 + m * 16;
#pragma unroll
      for (int r = 0; r < 4; ++r)
        C[(size_t)(gr + r) * N_TOTAL + gc] = acc[m][n][r] * s + bv;
    }
  }
#undef GLL
}

// Fallback if workspace is too small: correct but slow.
__global__ void naive_int4_kernel(const float* __restrict__ x,
                                  const int* __restrict__ wq,
                                  const float* __restrict__ scales,
                                  const float* __restrict__ bias,
                                  float* __restrict__ out) {
  size_t idx = (size_t)blockIdx.x * blockDim.x + threadIdx.x;
  int o = (int)(idx & (N_TOTAL - 1));
  int m = (int)(idx >> 12);
  const float* xr = x + (size_t)m * K_TOTAL;
  const int* wrow = wq + (size_t)o * (K_TOTAL / 2);
  float acc = 0.f;
  for (int j = 0; j < K_TOTAL / 2; ++j) {
    int b = wrow[j];
    int lo = ((b & 0xF) ^ 8) - 8;
    int hi = (((b >> 4) & 0xF) ^ 8) - 8;
    acc += xr[2 * j] * (float)lo + xr[2 * j + 1] * (float)hi;
  }
  out[idx] = acc * scales[o] + bias[o];
}

extern "C" void kernel_launch(void* const* d_in, const int* in_sizes, int n_in,
                              void* d_out, int out_size, void* d_ws, size_t ws_size,
                              hipStream_t stream) {
  const float* x      = (const float*)d_in[0];
  const int*   wq     = (const int*)d_in[1];
  const float* scales = (const float*)d_in[2];
  const float* bias   = (const float*)d_in[3];
  float* out = (float*)d_out;

  const size_t needA = (size_t)M_TOTAL * K_TOTAL * sizeof(unsigned short);  // 128 MB
  const size_t needW = (size_t)N_TOTAL * K_TOTAL * sizeof(unsigned short);  //  32 MB

  if (d_ws != nullptr && ws_size >= needA + needW) {
    unsigned short* Ab = (unsigned short*)d_ws;
    unsigned short* Wb = (unsigned short*)((char*)d_ws + needA);
    cvt_x_kernel<<<2048, 256, 0, stream>>>(x, Ab);
    dequant_w_kernel<<<1024, 256, 0, stream>>>(wq, Wb);
    gemm256_kernel<<<(M_TOTAL / BM) * (N_TOTAL / BN), 512, 0, stream>>>(Ab, Wb, scales, bias, out);
  } else {
    const size_t total = (size_t)M_TOTAL * N_TOTAL;
    naive_int4_kernel<<<(unsigned)(total / 256), 256, 0, stream>>>(x, wq, scales, bias, out);
  }
}

// Round 3
// 559.517 us; speedup vs baseline: 1.4643x; 1.0625x over previous
//
#include <hip/hip_runtime.h>
#include <hip/hip_bf16.h>
#include <stdint.h>

#define M_TOTAL 16384   // BATCH * SEQ
#define N_TOTAL 4096    // OUT_FEATURES
#define K_TOTAL 4096    // IN_FEATURES

#define BM 256
#define BN 256
#define BK 64
#define NT (K_TOTAL / BK)   // 64 K-steps

typedef __attribute__((ext_vector_type(4))) float f32x4;
typedef __attribute__((ext_vector_type(4))) int   i32x4;
typedef __attribute__((ext_vector_type(8))) short s16x8;
typedef __attribute__((ext_vector_type(4))) short s16x4;

__device__ __forceinline__ unsigned short f32_to_bf16_rne(float f) {
  union { float f; unsigned u; } c; c.f = f;
  unsigned r = (c.u + 0x7fffu + ((c.u >> 16) & 1u)) >> 16;
  return (unsigned short)r;
}

// x fp32 (M,K) -> bf16 (M,K)
__global__ void cvt_x_kernel(const float* __restrict__ x,
                             unsigned short* __restrict__ xb) {
  const int n4 = M_TOTAL * (K_TOTAL / 4);
  int idx = blockIdx.x * blockDim.x + threadIdx.x;
  int stride = gridDim.x * blockDim.x;
  const f32x4* xv = (const f32x4*)x;
  s16x4* ov = (s16x4*)xb;
  for (int i = idx; i < n4; i += stride) {
    f32x4 v = xv[i];
    s16x4 o;
#pragma unroll
    for (int j = 0; j < 4; ++j) o[j] = (short)f32_to_bf16_rne(v[j]);
    ov[i] = o;
  }
}

// packed int4 (one byte per int32 elem) -> bf16 integer values (N, K) row-major.
__global__ void dequant_w_kernel(const int* __restrict__ wq,
                                 unsigned short* __restrict__ wb) {
  const int n = (N_TOTAL * (K_TOTAL / 2)) / 4;
  int idx = blockIdx.x * blockDim.x + threadIdx.x;
  int stride = gridDim.x * blockDim.x;
  const i32x4* wv = (const i32x4*)wq;
  s16x8* ov = (s16x8*)wb;
  for (int i = idx; i < n; i += stride) {
    i32x4 w = wv[i];
    s16x8 o;
#pragma unroll
    for (int j = 0; j < 4; ++j) {
      int b = w[j];
      int lo = ((b & 0xF) ^ 8) - 8;
      int hi = (((b >> 4) & 0xF) ^ 8) - 8;
      union { float f; unsigned u; } cl, ch;
      cl.f = (float)lo; ch.f = (float)hi;
      o[2 * j]     = (short)(cl.u >> 16);
      o[2 * j + 1] = (short)(ch.u >> 16);
    }
    ov[i] = o;
  }
}

// 256x256 tile, BK=64, 8 waves (2x4), counted vmcnt+lgkmcnt pipelined,
// T2 LDS swizzle, split-A read so MFMA overlaps LDS reads within each wave.
__global__ __launch_bounds__(512, 2) void gemm256_kernel(
    const unsigned short* __restrict__ A,   // M x K bf16
    const unsigned short* __restrict__ B,   // N x K bf16 (int values)
    const float* __restrict__ scales,
    const float* __restrict__ bias,
    float* __restrict__ C) {
  // [buf][A=0/B=1][256 rows][64 cols] bf16 = 128 KB total
  __shared__ unsigned short lds[2][2][BM * BK];

  const int t  = threadIdx.x;
  const int l  = t & 63;
  const int w  = t >> 6;        // wave 0..7
  const int wm = w >> 2;        // 0..1 (M half)
  const int wn = w & 3;         // 0..3 (N quarter)
  const int fr = l & 15;
  const int kg = l >> 4;        // 0..3
  const int sx = fr & 7;        // swizzle XOR (row&7 == fr&7 for all frags)

  // T1/L2 swizzle: each XCD (wg&7) owns an exclusive 8-tile A block and
  // sweeps bn -> A fetched from HBM exactly once chip-wide; B L3-resident.
  const int wg = blockIdx.x;                 // nwg = 1024
  const int bm = (wg & 7) * 8 + ((wg >> 3) & 7);   // 0..63
  const int bn = wg >> 6;                          // 0..15

  // Staging: linear LDS dest (global_load_lds), pre-swizzled global source.
  // Lane l stores (row = g*64 + w*8 + (l>>3), slot = l&7); that slot must
  // hold logical slot (l&7) ^ (row&7) = (l&7) ^ (l>>3).
  const int rr   = l >> 3;
  const int ssrc = (l & 7) ^ rr;
  const unsigned short* pa = A + (size_t)(bm * BM + w * 8 + rr) * K_TOTAL + ssrc * 8;
  const unsigned short* pb = B + (size_t)(bn * BN + w * 8 + rr) * K_TOTAL + ssrc * 8;
  const int lds_off = w * 512 + l * 8;   // ushort units: w*1024B + l*16B

#define GLL(gp, lp) __builtin_amdgcn_global_load_lds( \
      (const __attribute__((address_space(1))) unsigned int*)(gp), \
      (__attribute__((address_space(3))) unsigned int*)(lp), 16, 0, 0)

  auto stage = [&](int buf, int kt) {
#pragma unroll
    for (int g = 0; g < 4; ++g) {
      GLL(pa + (size_t)g * 64 * K_TOTAL + kt, &lds[buf][0][lds_off + g * 4096]);
      GLL(pb + (size_t)g * 64 * K_TOTAL + kt, &lds[buf][1][lds_off + g * 4096]);
    }
  };

  f32x4 acc[8][4] = {};

  stage(0, 0);
  stage(1, BK);

  for (int t0 = 0; t0 < NT; ++t0) {
    // T4: counted vmcnt — buf[cur]'s 8 loads landed; other 8 stay in flight.
    if (t0 + 1 < NT) { asm volatile("s_waitcnt vmcnt(8)" ::: "memory"); }
    else             { asm volatile("s_waitcnt vmcnt(0)" ::: "memory"); }
    __builtin_amdgcn_sched_barrier(0);
    __builtin_amdgcn_s_barrier();           // barrier-A: buf[cur] fully staged
    __builtin_amdgcn_sched_barrier(0);

    const int cur = t0 & 1;
    const unsigned short* Abp = &lds[cur][0][(wm * 128 + fr) * BK];
    const unsigned short* Bbp = &lds[cur][1][(wn * 64 + fr) * BK];
    s16x8 bfr[4][2], af0[4][2], af1[4][2];

    // Group 1: all B frags + A-half 0  (16 ds_read_b128)
#pragma unroll
    for (int kh = 0; kh < 2; ++kh) {
      const int so = ((kh * 4 + kg) ^ sx) * 8;   // T2 swizzled slot
#pragma unroll
      for (int n = 0; n < 4; ++n)
        bfr[n][kh] = *(const s16x8*)&Bbp[n * 16 * BK + so];
#pragma unroll
      for (int m = 0; m < 4; ++m)
        af0[m][kh] = *(const s16x8*)&Abp[(m * 16) * BK + so];
    }
    __builtin_amdgcn_sched_barrier(0);
    // Group 2: A-half 1 (8 ds_read_b128) — stays outstanding under MFMA0
#pragma unroll
    for (int kh = 0; kh < 2; ++kh) {
      const int so = ((kh * 4 + kg) ^ sx) * 8;
#pragma unroll
      for (int m = 0; m < 4; ++m)
        af1[m][kh] = *(const s16x8*)&Abp[((m + 4) * 16) * BK + so];
    }
    __builtin_amdgcn_sched_barrier(0);
    asm volatile("s_waitcnt lgkmcnt(8)" ::: "memory");  // group 1 complete
    __builtin_amdgcn_sched_barrier(0);

    __builtin_amdgcn_s_setprio(1);          // MFMA0 overlaps group-2 reads
#pragma unroll
    for (int kh = 0; kh < 2; ++kh)
#pragma unroll
      for (int m = 0; m < 4; ++m)
#pragma unroll
        for (int n = 0; n < 4; ++n)
          acc[m][n] = __builtin_amdgcn_mfma_f32_16x16x32_bf16(af0[m][kh], bfr[n][kh],
                                                              acc[m][n], 0, 0, 0);
    __builtin_amdgcn_s_setprio(0);
    __builtin_amdgcn_sched_barrier(0);

    asm volatile("s_waitcnt lgkmcnt(0)" ::: "memory");  // all reads complete
    __builtin_amdgcn_sched_barrier(0);
    __builtin_amdgcn_s_barrier();           // barrier-B: every wave done reading
    __builtin_amdgcn_sched_barrier(0);

    if (t0 + 2 < NT) stage(cur, (t0 + 2) * BK);   // overwrite consumed buffer

    __builtin_amdgcn_s_setprio(1);          // MFMA1 overlaps staging in flight
#pragma unroll
    for (int kh = 0; kh < 2; ++kh)
#pragma unroll
      for (int m = 0; m < 4; ++m)
#pragma unroll
        for (int n = 0; n < 4; ++n)
          acc[m + 4][n] = __builtin_amdgcn_mfma_f32_16x16x32_bf16(af1[m][kh], bfr[n][kh],
                                                                  acc[m + 4][n], 0, 0, 0);
    __builtin_amdgcn_s_setprio(0);
  }

  // Epilogue: C/D layout col = lane&15, row = (lane>>4)*4 + reg.
  const int row0 = bm * BM + wm * 128 + kg * 4;
  const int col0 = bn * BN + wn * 64 + fr;
#pragma unroll
  for (int n = 0; n < 4; ++n) {
    const int gc = col0 + n * 16;
    const float s  = scales[gc];
    const float bv = bias[gc];
#pragma unroll
    for (int m = 0; m < 8; ++m) {
      const int gr = row0 + m * 16;
#pragma unroll
      for (int r = 0; r < 4; ++r)
        C[(size_t)(gr + r) * N_TOTAL + gc] = acc[m][n][r] * s + bv;
    }
  }
#undef GLL
}

// Fallback if workspace is too small: correct but slow.
__global__ void naive_int4_kernel(const float* __restrict__ x,
                                  const int* __restrict__ wq,
                                  const float* __restrict__ scales,
                                  const float* __restrict__ bias,
                                  float* __restrict__ out) {
  size_t idx = (size_t)blockIdx.x * blockDim.x + threadIdx.x;
  int o = (int)(idx & (N_TOTAL - 1));
  int m = (int)(idx >> 12);
  const float* xr = x + (size_t)m * K_TOTAL;
  const int* wrow = wq + (size_t)o * (K_TOTAL / 2);
  float acc = 0.f;
  for (int j = 0; j < K_TOTAL / 2; ++j) {
    int b = wrow[j];
    int lo = ((b & 0xF) ^ 8) - 8;
    int hi = (((b >> 4) & 0xF) ^ 8) - 8;
    acc += xr[2 * j] * (float)lo + xr[2 * j + 1] * (float)hi;
  }
  out[idx] = acc * scales[o] + bias[o];
}

extern "C" void kernel_launch(void* const* d_in, const int* in_sizes, int n_in,
                              void* d_out, int out_size, void* d_ws, size_t ws_size,
                              hipStream_t stream) {
  const float* x      = (const float*)d_in[0];
  const int*   wq     = (const int*)d_in[1];
  const float* scales = (const float*)d_in[2];
  const float* bias   = (const float*)d_in[3];
  float* out = (float*)d_out;

  const size_t needA = (size_t)M_TOTAL * K_TOTAL * sizeof(unsigned short);  // 128 MB
  const size_t needW = (size_t)N_TOTAL * K_TOTAL * sizeof(unsigned short);  //  32 MB

  if (d_ws != nullptr && ws_size >= needA + needW) {
    unsigned short* Ab = (unsigned short*)d_ws;
    unsigned short* Wb = (unsigned short*)((char*)d_ws + needA);
    cvt_x_kernel<<<2048, 256, 0, stream>>>(x, Ab);
    dequant_w_kernel<<<1024, 256, 0, stream>>>(wq, Wb);
    gemm256_kernel<<<(M_TOTAL / BM) * (N_TOTAL / BN), 512, 0, stream>>>(Ab, Wb, scales, bias, out);
  } else {
    const size_t total = (size_t)M_TOTAL * N_TOTAL;
    naive_int4_kernel<<<(unsigned)(total / 256), 256, 0, stream>>>(x, wq, scales, bias, out);
  }
}